// Round 9
// baseline (327.358 us; speedup 1.0000x reference)
//
#include <hip/hip_runtime.h>
#include <hip/hip_bf16.h>
#include <stdint.h>

typedef __bf16 bf16x8 __attribute__((ext_vector_type(8)));
typedef float  f32x4  __attribute__((ext_vector_type(4)));

__device__ __forceinline__ int imin(int a, int b) { return a < b ? a : b; }
__device__ __forceinline__ int imax(int a, int b) { return a > b ? a : b; }

#define TMASK ((1u << 19) - 1u)

__constant__ int cRES[16] = {16, 23, 31, 43, 59, 81, 112, 154,
                             213, 295, 407, 562, 777, 1073, 1483, 2048};

// ---------- prep: pack the 20 MFMA B-fragments (bf16x8 per lane) into ws ----------
// Fragment order: f0-3 W1[n4], f4-5 W2[kc], f6-9 WIN[n4], f10-17 WH[kc*4+n4],
// f18-19 WOUT[kc] (cols >=3 zeroed). Layout: wf[f*64 + lane] (16B each).
__global__ void __launch_bounds__(64) prep_wfrag(
    const float* __restrict__ W1, const float* __restrict__ W2,
    const float* __restrict__ WIN, const float* __restrict__ WH,
    const float* __restrict__ WOUT, uint4* __restrict__ wf)
{
    const int lane = threadIdx.x;
    const int c = lane & 15, g = lane >> 4;
    bf16x8 f;
    #pragma unroll
    for (int n4 = 0; n4 < 4; ++n4) {
        #pragma unroll
        for (int j = 0; j < 8; ++j) f[j] = (__bf16)W1[(g * 8 + j) * 64 + n4 * 16 + c];
        wf[n4 * 64 + lane] = *reinterpret_cast<uint4*>(&f);
    }
    #pragma unroll
    for (int kc = 0; kc < 2; ++kc) {
        #pragma unroll
        for (int j = 0; j < 8; ++j) f[j] = (__bf16)W2[(kc * 32 + g * 8 + j) * 16 + c];
        wf[(4 + kc) * 64 + lane] = *reinterpret_cast<uint4*>(&f);
    }
    #pragma unroll
    for (int n4 = 0; n4 < 4; ++n4) {
        #pragma unroll
        for (int j = 0; j < 8; ++j) f[j] = (__bf16)WIN[(g * 8 + j) * 64 + n4 * 16 + c];
        wf[(6 + n4) * 64 + lane] = *reinterpret_cast<uint4*>(&f);
    }
    #pragma unroll
    for (int kc = 0; kc < 2; ++kc)
        #pragma unroll
        for (int n4 = 0; n4 < 4; ++n4) {
            #pragma unroll
            for (int j = 0; j < 8; ++j) f[j] = (__bf16)WH[(kc * 32 + g * 8 + j) * 64 + n4 * 16 + c];
            wf[(10 + kc * 4 + n4) * 64 + lane] = *reinterpret_cast<uint4*>(&f);
        }
    #pragma unroll
    for (int kc = 0; kc < 2; ++kc) {
        #pragma unroll
        for (int j = 0; j < 8; ++j)
            f[j] = (c < 3) ? (__bf16)WOUT[(kc * 32 + g * 8 + j) * 3 + c] : (__bf16)0.0f;
        wf[(18 + kc) * 64 + lane] = *reinterpret_cast<uint4*>(&f);
    }
}

// ---------- fused: hash-gather (per-lane, 4 levels) + MFMA MLP chain ----------
// Wave = 16 points (tile). Lane (c,g): point c, levels 4g..4g+3 -> A1 fragment
// packed directly from trilinear interp (no enc round-trip). Then the proven
// 20x mfma_f32_16x16x32_bf16 chain with per-wave LDS [16][68] transposes.
// Gather latency of some waves overlaps MFMA/LDS of others (TA vs matrix pipes).
__global__ void __launch_bounds__(256) ngp_fused(
    const float* __restrict__ xin,
    const float* __restrict__ din,
    const float2* __restrict__ tab,
    const uint4* __restrict__ wf,
    float* __restrict__ out,
    int n)
{
    __shared__ float lds[4][16 * 68];
    const int tid  = threadIdx.x;
    const int wid  = tid >> 6;
    const int lane = tid & 63;
    const int c = lane & 15;
    const int g = lane >> 4;
    float* buf = &lds[wid][0];
    const int pbase = blockIdx.x * 64 + wid * 16;
    const int pc = pbase + c;

    // ---- phase 1: hash + 32 batched gathers (levels 4g..4g+3) ----
    const float xn0 = (xin[3 * pc + 0] + 1.0f) * 0.5f;
    const float xn1 = (xin[3 * pc + 1] + 1.0f) * 0.5f;
    const float xn2 = (xin[3 * pc + 2] + 1.0f) * 0.5f;

    uint32_t idx[4][8];
    float wa[4][3];
    #pragma unroll
    for (int m = 0; m < 4; ++m) {
        const int lv = 4 * g + m;
        const int rm = cRES[lv] - 1;
        const float rf = (float)rm;
        const uint32_t base = (uint32_t)lv << 19;

        const float p0 = xn0 * rf, p1 = xn1 * rf, p2 = xn2 * rf;
        const float f0 = floorf(p0), f1 = floorf(p1), f2 = floorf(p2);
        const int i0 = (int)f0, i1 = (int)f1, i2 = (int)f2;
        wa[m][0] = p0 - f0; wa[m][1] = p1 - f1; wa[m][2] = p2 - f2;

        const int a0 = imax(imin(i0, rm), 0), b0 = imax(imin(i0 + 1, rm), 0);
        const int a1i = imax(imin(i1, rm), 0), b1 = imax(imin(i1 + 1, rm), 0);
        const int a2 = imax(imin(i2, rm), 0), b2 = imax(imin(i2 + 1, rm), 0);

        const uint32_t t0a = (uint32_t)a0;
        const uint32_t t0b = (uint32_t)b0;
        const uint32_t t1a = (uint32_t)a1i * 2654435761u;
        const uint32_t t1b = (uint32_t)b1 * 2654435761u;
        const uint32_t t2a = (uint32_t)a2 * 805459861u;
        const uint32_t t2b = (uint32_t)b2 * 805459861u;

        idx[m][0] = base + ((t0a ^ t1a ^ t2a) & TMASK);
        idx[m][1] = base + ((t0b ^ t1a ^ t2a) & TMASK);
        idx[m][2] = base + ((t0a ^ t1b ^ t2a) & TMASK);
        idx[m][3] = base + ((t0b ^ t1b ^ t2a) & TMASK);
        idx[m][4] = base + ((t0a ^ t1a ^ t2b) & TMASK);
        idx[m][5] = base + ((t0b ^ t1a ^ t2b) & TMASK);
        idx[m][6] = base + ((t0a ^ t1b ^ t2b) & TMASK);
        idx[m][7] = base + ((t0b ^ t1b ^ t2b) & TMASK);
    }

    float2 v[4][8];
    #pragma unroll
    for (int m = 0; m < 4; ++m)
        #pragma unroll
        for (int cor = 0; cor < 8; ++cor)
            v[m][cor] = tab[idx[m][cor]];

    __builtin_amdgcn_sched_barrier(0);   // keep the gather batch above consumers

    bf16x8 a1;
    #pragma unroll
    for (int m = 0; m < 4; ++m) {
        const float w0 = wa[m][0], w1 = wa[m][1], w2 = wa[m][2];
        const float u0 = 1.0f - w0, u1 = 1.0f - w1, u2 = 1.0f - w2;
        float e0 = 0.0f, e1 = 0.0f;
        {   float cw = u0 * u1 * u2;  e0 = fmaf(v[m][0].x, cw, e0); e1 = fmaf(v[m][0].y, cw, e1); }
        {   float cw = w0 * u1 * u2;  e0 = fmaf(v[m][1].x, cw, e0); e1 = fmaf(v[m][1].y, cw, e1); }
        {   float cw = u0 * w1 * u2;  e0 = fmaf(v[m][2].x, cw, e0); e1 = fmaf(v[m][2].y, cw, e1); }
        {   float cw = w0 * w1 * u2;  e0 = fmaf(v[m][3].x, cw, e0); e1 = fmaf(v[m][3].y, cw, e1); }
        {   float cw = u0 * u1 * w2;  e0 = fmaf(v[m][4].x, cw, e0); e1 = fmaf(v[m][4].y, cw, e1); }
        {   float cw = w0 * u1 * w2;  e0 = fmaf(v[m][5].x, cw, e0); e1 = fmaf(v[m][5].y, cw, e1); }
        {   float cw = u0 * w1 * w2;  e0 = fmaf(v[m][6].x, cw, e0); e1 = fmaf(v[m][6].y, cw, e1); }
        {   float cw = w0 * w1 * w2;  e0 = fmaf(v[m][7].x, cw, e0); e1 = fmaf(v[m][7].y, cw, e1); }
        a1[2 * m]     = (__bf16)e0;
        a1[2 * m + 1] = (__bf16)e1;
    }

    // ---- phase 2: weight fragments (L1-resident after first tile per CU) ----
    #define LDW(f_) (*reinterpret_cast<const bf16x8*>(&wf[(f_) * 64 + lane]))
    bf16x8 w1f[4], w2f[2], winf[4], whf[2][4], woutf[2];
    #pragma unroll
    for (int n4 = 0; n4 < 4; ++n4) w1f[n4] = LDW(n4);
    #pragma unroll
    for (int kc = 0; kc < 2; ++kc) w2f[kc] = LDW(4 + kc);
    #pragma unroll
    for (int n4 = 0; n4 < 4; ++n4) winf[n4] = LDW(6 + n4);
    #pragma unroll
    for (int kc = 0; kc < 2; ++kc)
        #pragma unroll
        for (int n4 = 0; n4 < 4; ++n4) whf[kc][n4] = LDW(10 + kc * 4 + n4);
    #pragma unroll
    for (int kc = 0; kc < 2; ++kc) woutf[kc] = LDW(18 + kc);
    #undef LDW

    // ---- phase 3: MFMA chain (proven r8 structure) ----
    // layer 1: D1 = A1 @ W1 ; relu -> LDS [pt][feat]
    #pragma unroll
    for (int n4 = 0; n4 < 4; ++n4) {
        f32x4 d = {0.f, 0.f, 0.f, 0.f};
        d = __builtin_amdgcn_mfma_f32_16x16x32_bf16(a1, w1f[n4], d, 0, 0, 0);
        #pragma unroll
        for (int r = 0; r < 4; ++r)
            buf[(g * 4 + r) * 68 + n4 * 16 + c] = fmaxf(d[r], 0.0f);
    }

    // layer 2: h = relu(h1) @ W2
    f32x4 hacc = {0.f, 0.f, 0.f, 0.f};
    #pragma unroll
    for (int kc = 0; kc < 2; ++kc) {
        bf16x8 a2;
        const float* src = &buf[c * 68 + kc * 32 + g * 8];
        #pragma unroll
        for (int j = 0; j < 8; ++j) a2[j] = (__bf16)src[j];
        hacc = __builtin_amdgcn_mfma_f32_16x16x32_bf16(a2, w2f[kc], hacc, 0, 0, 0);
    }

    if (c == 0) {
        #pragma unroll
        for (int r = 0; r < 4; ++r)
            out[pbase + g * 4 + r] = __expf(hacc[r]);
    }

    #pragma unroll
    for (int r = 0; r < 4; ++r)
        buf[(g * 4 + r) * 68 + c] = hacc[r];

    // SH degree 4
    const float dx = din[3 * pc + 0];
    const float dy = din[3 * pc + 1];
    const float dz = din[3 * pc + 2];
    const float xy = dx * dy, xz = dx * dz, yz = dy * dz;
    const float x2 = dx * dx, y2 = dy * dy, z2 = dz * dz;
    float shv[16];
    shv[0]  = 0.28209479177387814f;
    shv[1]  = -0.48860251190291987f * dy;
    shv[2]  = 0.48860251190291987f * dz;
    shv[3]  = -0.48860251190291987f * dx;
    shv[4]  = 1.0925484305920792f * xy;
    shv[5]  = -1.0925484305920792f * yz;
    shv[6]  = 0.94617469575756f * z2 - 0.31539156525252f;
    shv[7]  = -1.0925484305920792f * xz;
    shv[8]  = 0.5462742152960396f * (x2 - y2);
    shv[9]  = 0.5900435899266435f * dy * (-3.0f * x2 + y2);
    shv[10] = 2.890611442640554f * xy * dz;
    shv[11] = 0.4570457994644657f * dy * (1.0f - 5.0f * z2);
    shv[12] = 0.3731763325901154f * dz * (5.0f * z2 - 3.0f);
    shv[13] = 0.4570457994644657f * dx * (1.0f - 5.0f * z2);
    shv[14] = 1.445305721320277f * dz * (x2 - y2);
    shv[15] = 0.5900435899266435f * dx * (-x2 + 3.0f * y2);

    // A3 = concat([sh, h])
    bf16x8 a3;
    if (g < 2) {
        #pragma unroll
        for (int j = 0; j < 8; ++j) a3[j] = (__bf16)shv[g * 8 + j];
    } else {
        const float* hsrc = &buf[c * 68 + (g - 2) * 8];
        #pragma unroll
        for (int j = 0; j < 8; ++j) a3[j] = (__bf16)hsrc[j];
    }

    // layer 3
    #pragma unroll
    for (int n4 = 0; n4 < 4; ++n4) {
        f32x4 d = {0.f, 0.f, 0.f, 0.f};
        d = __builtin_amdgcn_mfma_f32_16x16x32_bf16(a3, winf[n4], d, 0, 0, 0);
        #pragma unroll
        for (int r = 0; r < 4; ++r)
            buf[(g * 4 + r) * 68 + n4 * 16 + c] = fmaxf(d[r], 0.0f);
    }

    // layer 4
    bf16x8 a4[2];
    #pragma unroll
    for (int kc = 0; kc < 2; ++kc) {
        const float* src = &buf[c * 68 + kc * 32 + g * 8];
        #pragma unroll
        for (int j = 0; j < 8; ++j) a4[kc][j] = (__bf16)src[j];
    }
    f32x4 d4[4];
    #pragma unroll
    for (int n4 = 0; n4 < 4; ++n4) d4[n4] = (f32x4){0.f, 0.f, 0.f, 0.f};
    #pragma unroll
    for (int kc = 0; kc < 2; ++kc)
        #pragma unroll
        for (int n4 = 0; n4 < 4; ++n4)
            d4[n4] = __builtin_amdgcn_mfma_f32_16x16x32_bf16(a4[kc], whf[kc][n4], d4[n4], 0, 0, 0);
    #pragma unroll
    for (int n4 = 0; n4 < 4; ++n4)
        #pragma unroll
        for (int r = 0; r < 4; ++r)
            buf[(g * 4 + r) * 68 + n4 * 16 + c] = fmaxf(d4[n4][r], 0.0f);

    // layer 5 + sigmoid
    f32x4 d5 = {0.f, 0.f, 0.f, 0.f};
    #pragma unroll
    for (int kc = 0; kc < 2; ++kc) {
        bf16x8 a5;
        const float* src = &buf[c * 68 + kc * 32 + g * 8];
        #pragma unroll
        for (int j = 0; j < 8; ++j) a5[j] = (__bf16)src[j];
        d5 = __builtin_amdgcn_mfma_f32_16x16x32_bf16(a5, woutf[kc], d5, 0, 0, 0);
    }
    if (c < 3) {
        #pragma unroll
        for (int r = 0; r < 4; ++r)
            out[n + 3 * (pbase + g * 4 + r) + c] = 1.0f / (1.0f + __expf(-d5[r]));
    }
}

extern "C" void kernel_launch(void* const* d_in, const int* in_sizes, int n_in,
                              void* d_out, int out_size, void* d_ws, size_t ws_size,
                              hipStream_t stream)
{
    const float* x    = (const float*)d_in[0];
    const float* d    = (const float*)d_in[1];
    const float* tb   = (const float*)d_in[2];
    const float* w1   = (const float*)d_in[3];
    const float* w2   = (const float*)d_in[4];
    const float* win  = (const float*)d_in[5];
    const float* wh   = (const float*)d_in[6];
    const float* wout = (const float*)d_in[7];

    const int n = in_sizes[0] / 3;   // 262144
    uint4* wf = (uint4*)d_ws;        // 20 KB of packed weight fragments

    prep_wfrag<<<1, 64, 0, stream>>>(w1, w2, win, wh, wout, wf);
    ngp_fused<<<n / 64, 256, 0, stream>>>(x, d, (const float2*)tb, wf,
                                          (float*)d_out, n);
}